// Round 2
// baseline (17569.038 us; speedup 1.0000x reference)
//
#include <hip/hip_runtime.h>
#include <hip/hip_bf16.h>
#include <cstdio>

#define TT 512
#define NN 64
#define CC 512
#define HH 1024
#define PP 512
#define GG 4096           // 4*H
#define MPRE (TT*NN)      // 32768
#define TC 256            // timesteps per chunk
#define TCM (TC*NN)       // pre-chunk leading dim (rows)

typedef __attribute__((ext_vector_type(8))) short short8;
typedef __attribute__((ext_vector_type(4))) float floatx4;

__device__ __forceinline__ unsigned short f2bf(float f) {
  union { float f; unsigned u; } v; v.f = f;
  unsigned r = v.u + 0x7fffu + ((v.u >> 16) & 1u);
  return (unsigned short)(r >> 16);
}
__device__ __forceinline__ float bf2f(unsigned short u) {
  union { unsigned u; float f; } v; v.u = ((unsigned)u) << 16; return v.f;
}
__device__ __forceinline__ float sigm(float x) { return 1.f / (1.f + __expf(-x)); }
__device__ __forceinline__ float tanha(float x) { return 1.f - 2.f / (__expf(2.f * x) + 1.f); }

typedef const __attribute__((address_space(1))) void gvoid_t;
typedef __attribute__((address_space(3))) void lvoid_t;
__device__ __forceinline__ void gl2lds16(const void* g, void* l) {
  __builtin_amdgcn_global_load_lds((gvoid_t*)g, (lvoid_t*)l, 16, 0, 0);
}

__global__ void cast_f32_bf16(const float* __restrict__ src, unsigned short* __restrict__ dst, int n) {
  int i = (blockIdx.x * 256 + threadIdx.x) * 4;
  if (i < n) {
    float4 v = *(const float4*)(src + i);
    ushort4 o;
    o.x = f2bf(v.x); o.y = f2bf(v.y); o.z = f2bf(v.z); o.w = f2bf(v.w);
    *(ushort4*)(dst + i) = o;
  }
}

// dst[h][p] = (bf16) src[p][h]   (src is wo_w: P x H)
__global__ void transpose_cast(const float* __restrict__ src, unsigned short* __restrict__ dst) {
  int idx = blockIdx.x * 256 + threadIdx.x;
  if (idx < HH * PP) {
    int h = idx >> 9, p = idx & 511;
    dst[idx] = f2bf(src[p * HH + h]);
  }
}

// C[m][n] = sum_k A[m][k]*B[n][k] (+bias[n]); A: M x K, B: N x K, bf16, K%32==0, M,N%128==0.
// writeT: C stored transposed (C[n][m], leading dim M) -- pre is consumed column-major in time.
__global__ __launch_bounds__(256) void gemm_bt(
    const unsigned short* __restrict__ A, const unsigned short* __restrict__ B,
    const float* __restrict__ bias, unsigned short* __restrict__ C,
    int M, int N, int K, int writeT)
{
  __shared__ __align__(16) unsigned short As[128 * 32];
  __shared__ __align__(16) unsigned short Bs[128 * 32];
  const int tid = threadIdx.x;
  const int l = tid & 63, w = tid >> 6;
  const int wm = w >> 1, wn = w & 1;
  const int lane16 = l & 15, quad = l >> 4;
  const int rowA0 = blockIdx.x * 128, rowB0 = blockIdx.y * 128;
  floatx4 acc[4][4] = {};
  for (int kk = 0; kk < K; kk += 32) {
    __syncthreads();
#pragma unroll
    for (int r = 0; r < 2; ++r) {
      const int e = r * 256 + tid;          // ushort8 index within tile
      const int row = e >> 2, kgrp = (e & 3) << 3;
      gl2lds16(A + (size_t)(rowA0 + row) * K + kk + kgrp, As + (r * 256 + w * 64) * 8);
      gl2lds16(B + (size_t)(rowB0 + row) * K + kk + kgrp, Bs + (r * 256 + w * 64) * 8);
    }
    __syncthreads();
    short8 af[4], bf[4];
#pragma unroll
    for (int mt = 0; mt < 4; ++mt) af[mt] = *(const short8*)&As[(wm * 64 + mt * 16 + lane16) * 32 + quad * 8];
#pragma unroll
    for (int nt = 0; nt < 4; ++nt) bf[nt] = *(const short8*)&Bs[(wn * 64 + nt * 16 + lane16) * 32 + quad * 8];
#pragma unroll
    for (int mt = 0; mt < 4; ++mt)
#pragma unroll
      for (int nt = 0; nt < 4; ++nt)
        acc[mt][nt] = __builtin_amdgcn_mfma_f32_16x16x32_bf16(af[mt], bf[nt], acc[mt][nt], 0, 0, 0);
  }
#pragma unroll
  for (int mt = 0; mt < 4; ++mt) {
    const int m0 = rowA0 + wm * 64 + mt * 16 + quad * 4;
#pragma unroll
    for (int nt = 0; nt < 4; ++nt) {
      const int col = rowB0 + wn * 64 + nt * 16 + lane16;
      const float bv = bias ? bias[col] : 0.f;
      if (writeT) {
        ushort4 o;
        o.x = f2bf(acc[mt][nt][0] + bv); o.y = f2bf(acc[mt][nt][1] + bv);
        o.z = f2bf(acc[mt][nt][2] + bv); o.w = f2bf(acc[mt][nt][3] + bv);
        *(ushort4*)(C + (size_t)col * M + m0) = o;
      } else {
#pragma unroll
        for (int j = 0; j < 4; ++j) C[(size_t)(m0 + j) * N + col] = f2bf(acc[mt][nt][j] + bv);
      }
    }
  }
}

// Persistent recurrence over t in [t0, t1). 256 blocks x 256 threads, 1 grid-sync per step.
// Block b owns h in [b*4, b*4+4): computes the 16 gate columns (4 gates x 4 h) via MFMA
// with W_comb fragments in registers; also computes the (8x-replicated, write-deduped)
// out-projection tile p in [ (b&31)*16, +16 ) for the *previous* step (lagged by 1 barrier).
__global__ __launch_bounds__(256, 1) void lstm_rec(
    const unsigned short* __restrict__ preC,  // [4096][TCM] bf16 (pre chunk, transposed)
    const unsigned short* __restrict__ Wc,    // [4096][1024] bf16 (wr_w @ wo_w)
    const unsigned short* __restrict__ wo,    // [512][1024] bf16
    const float* __restrict__ wcp,            // [3072] peephole
    const void* __restrict__ lengths,         // int32 or int64 (auto-detected)
    unsigned short* __restrict__ act_buf,     // [2][64][1024] bf16 (zeroed before chunk 0)
    float* __restrict__ c_buf,                // [64][1024] f32 carry (zeroed before chunk 0)
    float* __restrict__ out,                  // [512][64][512]
    unsigned* __restrict__ bar,               // zeroed before chunk 0
    int t0, int t1, int last)
{
  __shared__ __align__(16) unsigned short wo_lds[16 * 1032]; // padded stride: 2-way banks (free)
  __shared__ float g_lds[64][17];
  const int tid = threadIdx.x, b = blockIdx.x;
  const int l = tid & 63, w = tid >> 6;
  const int lane16 = l & 15, quad = l >> 4;
  const int ptile = b & 31, kgr = b >> 5;

  const int* L32 = (const int*)lengths;
  const bool is64 = (L32[1] == 0);   // lengths>=1, so int64 layout shows 0 in odd words

  // stage wo rows [ptile*16, +16) into LDS (padded stride 1032)
  for (int r = 0; r < 8; ++r) {
    int e = r * 256 + tid;
    int row = e >> 7, k = (e & 127) << 3;
    *(short8*)&wo_lds[row * 1032 + k] = *(const short8*)&wo[(size_t)(ptile * 16 + row) * 1024 + k];
  }

  // W_comb fragments in registers: lane16 -> column lc = gate*4+hl
  short8 breg[32];
  {
    const int gate = lane16 >> 2, hl = lane16 & 3;
    const size_t ro = (size_t)(gate * 1024 + b * 4 + hl) * 1024 + quad * 8;
#pragma unroll
    for (int ks = 0; ks < 32; ++ks) breg[ks] = *(const short8*)&Wc[ro + ks * 32];
  }

  const int hglob = b * 4 + w;           // gate-math thread: (n=l, h=hglob)
  const float wci = wcp[hglob], wcf = wcp[1024 + hglob], wco = wcp[2048 + hglob];
  float c_state = c_buf[l * HH + hglob];
  __syncthreads();

  unsigned gen = (unsigned)t0;
  for (int t = t0; t <= t1; ++t) {
    if (t == t1 && !last) break;       // step t1-1's out-write is done by the next chunk
    const unsigned short* actP = act_buf + ((t + 1) & 1) * (NN * HH);
    floatx4 accg = {0.f, 0.f, 0.f, 0.f};
    floatx4 acco = {0.f, 0.f, 0.f, 0.f};
    const unsigned short* arow = actP + (size_t)(w * 16 + lane16) * HH + quad * 8;
    short8 abuf[2][4];
#pragma unroll
    for (int s = 0; s < 4; ++s) abuf[0][s] = *(const short8*)(arow + s * 32);
#pragma unroll
    for (int s = 0; s < 4; ++s) abuf[1][s] = *(const short8*)(arow + (4 + s) * 32);
#pragma unroll
    for (int g = 0; g < 8; ++g) {
#pragma unroll
      for (int s = 0; s < 4; ++s) {
        const int ks = g * 4 + s;
        short8 av = abuf[g & 1][s];
        short8 bo = *(const short8*)&wo_lds[lane16 * 1032 + ks * 32 + quad * 8];
        accg = __builtin_amdgcn_mfma_f32_16x16x32_bf16(av, breg[ks], accg, 0, 0, 0);
        acco = __builtin_amdgcn_mfma_f32_16x16x32_bf16(av, bo, acco, 0, 0, 0);
      }
      if (g < 6) {
#pragma unroll
        for (int s = 0; s < 4; ++s) abuf[g & 1][s] = *(const short8*)(arow + ((g + 2) * 4 + s) * 32);
      }
    }

    if (t < t1) {
      // dump g tile (rows n, cols lc) to LDS, then per-(n,h) gate math
#pragma unroll
      for (int j = 0; j < 4; ++j) g_lds[w * 16 + quad * 4 + j][lane16] = accg[j];
      __syncthreads();
      float gv[4];
#pragma unroll
      for (int gate = 0; gate < 4; ++gate) {
        float pv = bf2f(preC[(size_t)(gate * 1024 + hglob) * TCM + (t - t0) * NN + l]);
        gv[gate] = g_lds[l][gate * 4 + w] + pv;
      }
      float ig = sigm(gv[0] + wci * c_state);
      float fg = sigm(gv[1] + wcf * c_state);
      float cc = fg * c_state + ig * tanha(gv[3]);
      float og = sigm(gv[2] + wco * cc);
      c_state = cc;
      act_buf[(t & 1) * (NN * HH) + l * HH + hglob] = f2bf(og * tanha(cc));
    }

    // lagged output write for step t-1: this block's replica writes rows [kgr*8, +8)
    if (t > 0 && w == (kgr >> 1) && (quad >> 1) == (kgr & 1)) {
      const int p = ptile * 16 + lane16;
#pragma unroll
      for (int j = 0; j < 4; ++j) {
        const int n = w * 16 + quad * 4 + j;
        const int ln = is64 ? (int)((const long long*)lengths)[n] : L32[n];
        out[(size_t)((t - 1) * NN + n) * PP + p] = ((t - 1) < ln) ? acco[j] : 0.f;
      }
    }

    if (t < t1) {
      __syncthreads();
      if (tid == 0) {
        __threadfence();
        unsigned old = __hip_atomic_fetch_add(&bar[0], 1u, __ATOMIC_ACQ_REL, __HIP_MEMORY_SCOPE_AGENT);
        if (old == gridDim.x - 1) {
          __hip_atomic_store(&bar[0], 0u, __ATOMIC_RELAXED, __HIP_MEMORY_SCOPE_AGENT);
          __hip_atomic_store(&bar[1], gen + 1u, __ATOMIC_RELEASE, __HIP_MEMORY_SCOPE_AGENT);
        } else {
          while (__hip_atomic_load(&bar[1], __ATOMIC_ACQUIRE, __HIP_MEMORY_SCOPE_AGENT) <= gen)
            __builtin_amdgcn_s_sleep(1);
        }
        __threadfence();
      }
      __syncthreads();
      ++gen;
    }
  }
  c_buf[l * HH + hglob] = c_state;
}

extern "C" void kernel_launch(void* const* d_in, const int* in_sizes, int n_in,
                              void* d_out, int out_size, void* d_ws, size_t ws_size,
                              hipStream_t stream) {
  (void)in_sizes; (void)n_in; (void)out_size;
  const float* x    = (const float*)d_in[0];
  const void*  len  = d_in[1];
  const float* wx_w = (const float*)d_in[2];
  const float* wx_b = (const float*)d_in[3];
  const float* wr_w = (const float*)d_in[4];
  const float* wo_w = (const float*)d_in[5];
  const float* wc   = (const float*)d_in[6];
  float* out = (float*)d_out;

  char* ws = (char*)d_ws; size_t off = 0;
  auto alloc = [&](size_t b) { void* p = ws + off; off += (b + 255) & ~(size_t)255; return p; };
  unsigned short* x_bf  = (unsigned short*)alloc((size_t)MPRE * CC * 2);   // 33.6 MB
  unsigned short* wx_bf = (unsigned short*)alloc((size_t)GG * CC * 2);     //  4.2 MB
  unsigned short* wr_bf = (unsigned short*)alloc((size_t)GG * PP * 2);     //  4.2 MB
  unsigned short* wo_bf = (unsigned short*)alloc((size_t)PP * HH * 2);     //  1.0 MB
  unsigned short* woT   = (unsigned short*)alloc((size_t)HH * PP * 2);     //  1.0 MB
  unsigned short* Wc_bf = (unsigned short*)alloc((size_t)GG * HH * 2);     //  8.4 MB
  unsigned short* preC  = (unsigned short*)alloc((size_t)GG * TCM * 2);    // 134 MB (per-chunk)
  unsigned short* act   = (unsigned short*)alloc((size_t)2 * NN * HH * 2); // contiguous with c_buf+bar
  float*          c_buf = (float*)alloc((size_t)NN * HH * 4);
  unsigned* bar = (unsigned*)alloc(256);
  if (off > ws_size) {
    fprintf(stderr, "kernel_launch: workspace too small (%zu needed, %zu given)\n", off, ws_size);
    return;
  }

  // zero act double-buffer + c carry + barrier (contiguous region)
  hipMemsetAsync(act, 0, (size_t)2 * NN * HH * 2 + (size_t)NN * HH * 4 + 256, stream);

  int n1 = MPRE * CC; cast_f32_bf16<<<dim3((n1 / 4 + 255) / 256), dim3(256), 0, stream>>>(x, x_bf, n1);
  int n2 = GG * CC;   cast_f32_bf16<<<dim3((n2 / 4 + 255) / 256), dim3(256), 0, stream>>>(wx_w, wx_bf, n2);
  int n3 = GG * PP;   cast_f32_bf16<<<dim3((n3 / 4 + 255) / 256), dim3(256), 0, stream>>>(wr_w, wr_bf, n3);
  int n4 = PP * HH;   cast_f32_bf16<<<dim3((n4 / 4 + 255) / 256), dim3(256), 0, stream>>>(wo_w, wo_bf, n4);
  transpose_cast<<<dim3((HH * PP + 255) / 256), dim3(256), 0, stream>>>(wo_w, woT);

  // W_comb = wr_w @ wo_w  (4096 x 1024), normal layout
  gemm_bt<<<dim3(GG / 128, HH / 128), dim3(256), 0, stream>>>(wr_bf, woT, nullptr, Wc_bf, GG, HH, PP, 0);

  for (int chunk = 0; chunk < TT / TC; ++chunk) {
    const int t0 = chunk * TC, t1 = t0 + TC;
    const int last = (t1 == TT) ? 1 : 0;
    // pre chunk = x[t0:t1] @ wx_w^T + wx_b, stored transposed [4096][TCM]
    gemm_bt<<<dim3(TCM / 128, GG / 128), dim3(256), 0, stream>>>(
        x_bf + (size_t)t0 * NN * CC, wx_bf, wx_b, preC, TCM, GG, CC, 1);

    const unsigned short* a0 = preC; const unsigned short* a1 = Wc_bf; const unsigned short* a2 = wo_bf;
    const float* a3 = wc; const void* a4 = len; unsigned short* a5 = act; float* a6c = c_buf;
    float* a7 = out; unsigned* a8 = bar; int a9 = t0, a10 = t1, a11 = last;
    void* args[12] = { &a0, &a1, &a2, &a3, &a4, &a5, &a6c, &a7, &a8, &a9, &a10, &a11 };
    hipLaunchCooperativeKernel((void*)lstm_rec, dim3(256), dim3(256), args, 0, stream);
  }
}

// Round 3
// 7200.674 us; speedup vs baseline: 2.4399x; 2.4399x over previous
//
#include <hip/hip_runtime.h>
#include <hip/hip_bf16.h>
#include <cstdio>

#define TT 512
#define NN 64
#define CC 512
#define HH 1024
#define PP 512
#define GG 4096           // 4*H
#define MPRE (TT*NN)      // 32768
#define TC 256            // timesteps per chunk
#define TCM (TC*NN)       // pre-chunk leading dim (rows)
#define NB 128            // recurrence blocks

typedef __attribute__((ext_vector_type(8))) short short8;
typedef __attribute__((ext_vector_type(4))) float floatx4;

__device__ __forceinline__ unsigned short f2bf(float f) {
  union { float f; unsigned u; } v; v.f = f;
  unsigned r = v.u + 0x7fffu + ((v.u >> 16) & 1u);
  return (unsigned short)(r >> 16);
}
__device__ __forceinline__ float bf2f(unsigned short u) {
  union { unsigned u; float f; } v; v.u = ((unsigned)u) << 16; return v.f;
}
__device__ __forceinline__ float sigm(float x) { return 1.f / (1.f + __expf(-x)); }
__device__ __forceinline__ float tanha(float x) { return 1.f - 2.f / (__expf(2.f * x) + 1.f); }

typedef const __attribute__((address_space(1))) void gvoid_t;
typedef __attribute__((address_space(3))) void lvoid_t;
__device__ __forceinline__ void gl2lds16(const void* g, void* l) {
  __builtin_amdgcn_global_load_lds((gvoid_t*)g, (lvoid_t*)l, 16, 0, 0);
}

__global__ void cast_f32_bf16(const float* __restrict__ src, unsigned short* __restrict__ dst, int n) {
  int i = (blockIdx.x * 256 + threadIdx.x) * 4;
  if (i < n) {
    float4 v = *(const float4*)(src + i);
    ushort4 o;
    o.x = f2bf(v.x); o.y = f2bf(v.y); o.z = f2bf(v.z); o.w = f2bf(v.w);
    *(ushort4*)(dst + i) = o;
  }
}

// dst[h][p] = (bf16) src[p][h]   (src is wo_w: P x H)
__global__ void transpose_cast(const float* __restrict__ src, unsigned short* __restrict__ dst) {
  int idx = blockIdx.x * 256 + threadIdx.x;
  if (idx < HH * PP) {
    int h = idx >> 9, p = idx & 511;
    dst[idx] = f2bf(src[p * HH + h]);
  }
}

// C[m][n] = sum_k A[m][k]*B[n][k] (+bias[n]); A: M x K, B: N x K, bf16, K%32==0, M,N%128==0.
// writeT: C stored transposed (C[n][m], leading dim M).
__global__ __launch_bounds__(256) void gemm_bt(
    const unsigned short* __restrict__ A, const unsigned short* __restrict__ B,
    const float* __restrict__ bias, unsigned short* __restrict__ C,
    int M, int N, int K, int writeT)
{
  __shared__ __align__(16) unsigned short As[128 * 32];
  __shared__ __align__(16) unsigned short Bs[128 * 32];
  const int tid = threadIdx.x;
  const int l = tid & 63, w = tid >> 6;
  const int wm = w >> 1, wn = w & 1;
  const int lane16 = l & 15, quad = l >> 4;
  const int rowA0 = blockIdx.x * 128, rowB0 = blockIdx.y * 128;
  floatx4 acc[4][4] = {};
  for (int kk = 0; kk < K; kk += 32) {
    __syncthreads();
#pragma unroll
    for (int r = 0; r < 2; ++r) {
      const int e = r * 256 + tid;
      const int row = e >> 2, kgrp = (e & 3) << 3;
      gl2lds16(A + (size_t)(rowA0 + row) * K + kk + kgrp, As + (r * 256 + w * 64) * 8);
      gl2lds16(B + (size_t)(rowB0 + row) * K + kk + kgrp, Bs + (r * 256 + w * 64) * 8);
    }
    __syncthreads();
    short8 af[4], bf[4];
#pragma unroll
    for (int mt = 0; mt < 4; ++mt) af[mt] = *(const short8*)&As[(wm * 64 + mt * 16 + lane16) * 32 + quad * 8];
#pragma unroll
    for (int nt = 0; nt < 4; ++nt) bf[nt] = *(const short8*)&Bs[(wn * 64 + nt * 16 + lane16) * 32 + quad * 8];
#pragma unroll
    for (int mt = 0; mt < 4; ++mt)
#pragma unroll
      for (int nt = 0; nt < 4; ++nt)
        acc[mt][nt] = __builtin_amdgcn_mfma_f32_16x16x32_bf16(af[mt], bf[nt], acc[mt][nt], 0, 0, 0);
  }
#pragma unroll
  for (int mt = 0; mt < 4; ++mt) {
    const int m0 = rowA0 + wm * 64 + mt * 16 + quad * 4;
#pragma unroll
    for (int nt = 0; nt < 4; ++nt) {
      const int col = rowB0 + wn * 64 + nt * 16 + lane16;
      const float bv = bias ? bias[col] : 0.f;
      if (writeT) {
        ushort4 o;
        o.x = f2bf(acc[mt][nt][0] + bv); o.y = f2bf(acc[mt][nt][1] + bv);
        o.z = f2bf(acc[mt][nt][2] + bv); o.w = f2bf(acc[mt][nt][3] + bv);
        *(ushort4*)(C + (size_t)col * M + m0) = o;
      } else {
#pragma unroll
        for (int j = 0; j < 4; ++j) C[(size_t)(m0 + j) * N + col] = f2bf(acc[mt][nt][j] + bv);
      }
    }
  }
}

// Persistent recurrence over t in [t0,t1). NB blocks x 256 threads.
// Block b owns h in [b*8, b*8+8). Weights in LDS; act exchanged via agent-coherent
// (L2-bypass) relaxed atomics so the grid barrier needs no cache maintenance.
// Barrier: monotone counter (no reset -> no reset/release reorder race).
__global__ __launch_bounds__(256, 1) void lstm_rec(
    const unsigned short* __restrict__ preC,  // [4096][TCM] bf16
    const unsigned short* __restrict__ Wc,    // [4096][1024] bf16 (wr_w @ wo_w)
    const unsigned short* __restrict__ wo,    // [512][1024] bf16
    const float* __restrict__ wcp,            // [3072] peephole
    const void* __restrict__ lengths,         // int32 or int64 (auto-detected)
    unsigned short* __restrict__ act_buf,     // [2][64][1024] bf16 (zeroed before chunk 0)
    float* __restrict__ c_buf,                // [64][1024] f32 carry
    float* __restrict__ out,                  // [512][64][512]
    unsigned* __restrict__ bar,               // zeroed before chunk 0
    int t0, int t1, int last)
{
  __shared__ __align__(16) unsigned short Wc_lds[32 * 1032]; // 66 KB
  __shared__ __align__(16) unsigned short wo_lds[16 * 1032]; // 33 KB
  __shared__ float g_lds[64][33];                            // 8.4 KB
  __shared__ __align__(16) unsigned short alds[64][8];       // 1 KB
  const int tid = threadIdx.x, b = blockIdx.x;
  const int l = tid & 63, w = tid >> 6;
  const int lane16 = l & 15, quad = l >> 4;
  const int ptile = b & 31, kgr = b >> 5;

  const int* L32 = (const int*)lengths;
  const bool is64 = (L32[1] == 0);

  // stage Wc: local row c=gate*8+hl <- Wc[gate*1024 + b*8 + hl]
  for (int r = 0; r < 16; ++r) {
    int e = r * 256 + tid;
    int row = e >> 7, k = (e & 127) << 3;
    int gate = row >> 3, hl = row & 7;
    *(short8*)&Wc_lds[row * 1032 + k] =
        *(const short8*)&Wc[(size_t)(gate * 1024 + b * 8 + hl) * 1024 + k];
  }
  // stage wo rows [ptile*16, +16)
  for (int r = 0; r < 8; ++r) {
    int e = r * 256 + tid;
    int row = e >> 7, k = (e & 127) << 3;
    *(short8*)&wo_lds[row * 1032 + k] =
        *(const short8*)&wo[(size_t)(ptile * 16 + row) * 1024 + k];
  }

  const int h0 = b * 8 + w, h1 = h0 + 4;     // gate-math: thread=(n=l, h0/h1)
  float c0 = c_buf[l * HH + h0], c1 = c_buf[l * HH + h1];
  const float wci0 = wcp[h0], wcf0 = wcp[1024 + h0], wco0 = wcp[2048 + h0];
  const float wci1 = wcp[h1], wcf1 = wcp[1024 + h1], wco1 = wcp[2048 + h1];
  __syncthreads();

  for (int t = t0; t <= t1; ++t) {
    if (t == t1 && !last) break;
    const bool gate_on = (t < t1);

    float pv0[4], pv1[4];
    if (gate_on) {
      const int trel = (t - t0) * NN + l;
#pragma unroll
      for (int g = 0; g < 4; ++g) {
        pv0[g] = bf2f(preC[(size_t)(g * 1024 + h0) * TCM + trel]);
        pv1[g] = bf2f(preC[(size_t)(g * 1024 + h1) * TCM + trel]);
      }
    }

    const unsigned short* actP = act_buf + ((t + 1) & 1) * (NN * HH);
    const unsigned long long* arow =
        (const unsigned long long*)(actP + (size_t)(w * 16 + lane16) * HH) + quad * 2;
    short8 frag[32];
#pragma unroll
    for (int ks = 0; ks < 32; ++ks) {
      unsigned long long lo = __hip_atomic_load(arow + ks * 8,     __ATOMIC_RELAXED, __HIP_MEMORY_SCOPE_AGENT);
      unsigned long long hi = __hip_atomic_load(arow + ks * 8 + 1, __ATOMIC_RELAXED, __HIP_MEMORY_SCOPE_AGENT);
      union { unsigned long long q[2]; short8 v; } u;
      u.q[0] = lo; u.q[1] = hi;
      frag[ks] = u.v;
    }

    floatx4 accg0 = {0.f, 0.f, 0.f, 0.f}, accg1 = {0.f, 0.f, 0.f, 0.f};
    floatx4 acco = {0.f, 0.f, 0.f, 0.f};
#pragma unroll
    for (int ks = 0; ks < 32; ++ks) {
      short8 b0 = *(const short8*)&Wc_lds[lane16 * 1032 + ks * 32 + quad * 8];
      short8 b1 = *(const short8*)&Wc_lds[(16 + lane16) * 1032 + ks * 32 + quad * 8];
      accg0 = __builtin_amdgcn_mfma_f32_16x16x32_bf16(frag[ks], b0, accg0, 0, 0, 0);
      accg1 = __builtin_amdgcn_mfma_f32_16x16x32_bf16(frag[ks], b1, accg1, 0, 0, 0);
    }
    if (w == kgr) {
#pragma unroll
      for (int ks = 0; ks < 32; ++ks) {
        short8 bo = *(const short8*)&wo_lds[lane16 * 1032 + ks * 32 + quad * 8];
        acco = __builtin_amdgcn_mfma_f32_16x16x32_bf16(frag[ks], bo, acco, 0, 0, 0);
      }
      if (t > 0) {   // lagged out write for step t-1: rows [kgr*16,+16), cols ptile
        const int p = ptile * 16 + lane16;
#pragma unroll
        for (int j = 0; j < 4; ++j) {
          const int n = kgr * 16 + quad * 4 + j;
          const int ln = is64 ? (int)((const long long*)lengths)[n] : L32[n];
          out[(size_t)((t - 1) * NN + n) * PP + p] = ((t - 1) < ln) ? acco[j] : 0.f;
        }
      }
    }

    if (gate_on) {
#pragma unroll
      for (int j = 0; j < 4; ++j) {
        g_lds[w * 16 + quad * 4 + j][lane16] = accg0[j];
        g_lds[w * 16 + quad * 4 + j][16 + lane16] = accg1[j];
      }
      __syncthreads();
      float gv0[4], gv1[4];
#pragma unroll
      for (int g = 0; g < 4; ++g) {
        gv0[g] = g_lds[l][g * 8 + w] + pv0[g];
        gv1[g] = g_lds[l][g * 8 + w + 4] + pv1[g];
      }
      {
        float ig = sigm(gv0[0] + wci0 * c0);
        float fg = sigm(gv0[1] + wcf0 * c0);
        float cc = fg * c0 + ig * tanha(gv0[3]);
        float og = sigm(gv0[2] + wco0 * cc);
        c0 = cc;
        alds[l][w] = f2bf(og * tanha(cc));
      }
      {
        float ig = sigm(gv1[0] + wci1 * c1);
        float fg = sigm(gv1[1] + wcf1 * c1);
        float cc = fg * c1 + ig * tanha(gv1[3]);
        float og = sigm(gv1[2] + wco1 * cc);
        c1 = cc;
        alds[l][w + 4] = f2bf(og * tanha(cc));
      }
      __syncthreads();
      if (w == 0) {   // coherent act store: 16 B per n-row owned by this block
        const unsigned long long* src = (const unsigned long long*)&alds[l][0];
        unsigned long long v0 = src[0], v1 = src[1];
        unsigned long long* dst =
            (unsigned long long*)(act_buf + (size_t)(t & 1) * (NN * HH) + (size_t)l * HH + b * 8);
        __hip_atomic_store(dst,     v0, __ATOMIC_RELAXED, __HIP_MEMORY_SCOPE_AGENT);
        __hip_atomic_store(dst + 1, v1, __ATOMIC_RELAXED, __HIP_MEMORY_SCOPE_AGENT);
      }
      if (tid == 0) {
        __atomic_signal_fence(__ATOMIC_SEQ_CST);
        __builtin_amdgcn_s_waitcnt(0);   // wave0's coherent stores reach the coherence point
        unsigned old = __hip_atomic_fetch_add(&bar[0], 1u, __ATOMIC_RELAXED, __HIP_MEMORY_SCOPE_AGENT);
        if (old == (unsigned)(t + 1) * NB - 1u) {
          __hip_atomic_store(&bar[1], (unsigned)(t + 1), __ATOMIC_RELAXED, __HIP_MEMORY_SCOPE_AGENT);
        } else {
          while (__hip_atomic_load(&bar[1], __ATOMIC_RELAXED, __HIP_MEMORY_SCOPE_AGENT) <= (unsigned)t)
            __builtin_amdgcn_s_sleep(2);
        }
        __atomic_signal_fence(__ATOMIC_SEQ_CST);
      }
      __syncthreads();
    }
  }
  c_buf[l * HH + h0] = c0;
  c_buf[l * HH + h1] = c1;
}

extern "C" void kernel_launch(void* const* d_in, const int* in_sizes, int n_in,
                              void* d_out, int out_size, void* d_ws, size_t ws_size,
                              hipStream_t stream) {
  (void)in_sizes; (void)n_in; (void)out_size;
  const float* x    = (const float*)d_in[0];
  const void*  len  = d_in[1];
  const float* wx_w = (const float*)d_in[2];
  const float* wx_b = (const float*)d_in[3];
  const float* wr_w = (const float*)d_in[4];
  const float* wo_w = (const float*)d_in[5];
  const float* wc   = (const float*)d_in[6];
  float* out = (float*)d_out;

  char* ws = (char*)d_ws; size_t off = 0;
  auto alloc = [&](size_t b) { void* p = ws + off; off += (b + 255) & ~(size_t)255; return p; };
  unsigned short* x_bf  = (unsigned short*)alloc((size_t)MPRE * CC * 2);
  unsigned short* wx_bf = (unsigned short*)alloc((size_t)GG * CC * 2);
  unsigned short* wr_bf = (unsigned short*)alloc((size_t)GG * PP * 2);
  unsigned short* wo_bf = (unsigned short*)alloc((size_t)PP * HH * 2);
  unsigned short* woT   = (unsigned short*)alloc((size_t)HH * PP * 2);
  unsigned short* Wc_bf = (unsigned short*)alloc((size_t)GG * HH * 2);
  unsigned short* preC  = (unsigned short*)alloc((size_t)GG * TCM * 2);
  unsigned short* act   = (unsigned short*)alloc((size_t)2 * NN * HH * 2);
  float*          c_buf = (float*)alloc((size_t)NN * HH * 4);
  unsigned* bar = (unsigned*)alloc(256);
  if (off > ws_size) {
    fprintf(stderr, "kernel_launch: workspace too small (%zu needed, %zu given)\n", off, ws_size);
    return;
  }

  // zero act double-buffer + c carry + barrier (contiguous region)
  hipMemsetAsync(act, 0, (size_t)2 * NN * HH * 2 + (size_t)NN * HH * 4 + 256, stream);

  int n1 = MPRE * CC; cast_f32_bf16<<<dim3((n1 / 4 + 255) / 256), dim3(256), 0, stream>>>(x, x_bf, n1);
  int n2 = GG * CC;   cast_f32_bf16<<<dim3((n2 / 4 + 255) / 256), dim3(256), 0, stream>>>(wx_w, wx_bf, n2);
  int n3 = GG * PP;   cast_f32_bf16<<<dim3((n3 / 4 + 255) / 256), dim3(256), 0, stream>>>(wr_w, wr_bf, n3);
  int n4 = PP * HH;   cast_f32_bf16<<<dim3((n4 / 4 + 255) / 256), dim3(256), 0, stream>>>(wo_w, wo_bf, n4);
  transpose_cast<<<dim3((HH * PP + 255) / 256), dim3(256), 0, stream>>>(wo_w, woT);

  // W_comb = wr_w @ wo_w  (4096 x 1024)
  gemm_bt<<<dim3(GG / 128, HH / 128), dim3(256), 0, stream>>>(wr_bf, woT, nullptr, Wc_bf, GG, HH, PP, 0);

  for (int chunk = 0; chunk < TT / TC; ++chunk) {
    const int t0 = chunk * TC, t1 = t0 + TC;
    const int last = (t1 == TT) ? 1 : 0;
    gemm_bt<<<dim3(TCM / 128, GG / 128), dim3(256), 0, stream>>>(
        x_bf + (size_t)t0 * NN * CC, wx_bf, wx_b, preC, TCM, GG, CC, 1);

    const unsigned short* a0 = preC; const unsigned short* a1 = Wc_bf; const unsigned short* a2 = wo_bf;
    const float* a3 = wc; const void* a4 = len; unsigned short* a5 = act; float* a6c = c_buf;
    float* a7 = out; unsigned* a8 = bar; int a9 = t0, a10 = t1, a11 = last;
    void* args[12] = { &a0, &a1, &a2, &a3, &a4, &a5, &a6c, &a7, &a8, &a9, &a10, &a11 };
    hipLaunchCooperativeKernel((void*)lstm_rec, dim3(NB), dim3(256), args, 0, stream);
  }
}

// Round 5
// 5425.122 us; speedup vs baseline: 3.2385x; 1.3273x over previous
//
#include <hip/hip_runtime.h>
#include <hip/hip_bf16.h>
#include <cstdio>

#define TT 512
#define NN 64
#define CC 512
#define HH 1024
#define PP 512
#define GG 4096           // 4*H
#define MPRE (TT*NN)      // 32768
#define TC 256            // timesteps per chunk
#define TCM (TC*NN)       // pre-chunk leading dim (rows)
#define NB 128            // recurrence blocks (8 h each)

typedef __attribute__((ext_vector_type(8))) short short8;
typedef __attribute__((ext_vector_type(4))) float floatx4;

__device__ __forceinline__ unsigned short f2bf(float f) {
  union { float f; unsigned u; } v; v.f = f;
  unsigned r = v.u + 0x7fffu + ((v.u >> 16) & 1u);
  return (unsigned short)(r >> 16);
}
__device__ __forceinline__ float bf2f(unsigned short u) {
  union { unsigned u; float f; } v; v.u = ((unsigned)u) << 16; return v.f;
}
__device__ __forceinline__ float sigm(float x) { return 1.f / (1.f + __expf(-x)); }
__device__ __forceinline__ float tanha(float x) { return 1.f - 2.f / (__expf(2.f * x) + 1.f); }

typedef const __attribute__((address_space(1))) void gvoid_t;
typedef __attribute__((address_space(3))) void lvoid_t;
__device__ __forceinline__ void gl2lds16(const void* g, void* l) {
  __builtin_amdgcn_global_load_lds((gvoid_t*)g, (lvoid_t*)l, 16, 0, 0);
}

__global__ void cast_f32_bf16(const float* __restrict__ src, unsigned short* __restrict__ dst, int n) {
  int i = (blockIdx.x * 256 + threadIdx.x) * 4;
  if (i < n) {
    float4 v = *(const float4*)(src + i);
    ushort4 o;
    o.x = f2bf(v.x); o.y = f2bf(v.y); o.z = f2bf(v.z); o.w = f2bf(v.w);
    *(ushort4*)(dst + i) = o;
  }
}

// dst[h][p] = (bf16) src[p][h]   (src is wo_w: P x H)
__global__ void transpose_cast(const float* __restrict__ src, unsigned short* __restrict__ dst) {
  int idx = blockIdx.x * 256 + threadIdx.x;
  if (idx < HH * PP) {
    int h = idx >> 9, p = idx & 511;
    dst[idx] = f2bf(src[p * HH + h]);
  }
}

// C[m][n] = sum_k A[m][k]*B[n][k] (+bias[n]); A: M x K, B: N x K, bf16.
// writeT: C stored transposed (C[n][m], leading dim M).
__global__ __launch_bounds__(256) void gemm_bt(
    const unsigned short* __restrict__ A, const unsigned short* __restrict__ B,
    const float* __restrict__ bias, unsigned short* __restrict__ C,
    int M, int N, int K, int writeT)
{
  __shared__ __align__(16) unsigned short As[128 * 32];
  __shared__ __align__(16) unsigned short Bs[128 * 32];
  const int tid = threadIdx.x;
  const int l = tid & 63, w = tid >> 6;
  const int wm = w >> 1, wn = w & 1;
  const int lane16 = l & 15, quad = l >> 4;
  const int rowA0 = blockIdx.x * 128, rowB0 = blockIdx.y * 128;
  floatx4 acc[4][4] = {};
  for (int kk = 0; kk < K; kk += 32) {
    __syncthreads();
#pragma unroll
    for (int r = 0; r < 2; ++r) {
      const int e = r * 256 + tid;
      const int row = e >> 2, kgrp = (e & 3) << 3;
      gl2lds16(A + (size_t)(rowA0 + row) * K + kk + kgrp, As + (r * 256 + w * 64) * 8);
      gl2lds16(B + (size_t)(rowB0 + row) * K + kk + kgrp, Bs + (r * 256 + w * 64) * 8);
    }
    __syncthreads();
    short8 af[4], bf[4];
#pragma unroll
    for (int mt = 0; mt < 4; ++mt) af[mt] = *(const short8*)&As[(wm * 64 + mt * 16 + lane16) * 32 + quad * 8];
#pragma unroll
    for (int nt = 0; nt < 4; ++nt) bf[nt] = *(const short8*)&Bs[(wn * 64 + nt * 16 + lane16) * 32 + quad * 8];
#pragma unroll
    for (int mt = 0; mt < 4; ++mt)
#pragma unroll
      for (int nt = 0; nt < 4; ++nt)
        acc[mt][nt] = __builtin_amdgcn_mfma_f32_16x16x32_bf16(af[mt], bf[nt], acc[mt][nt], 0, 0, 0);
  }
#pragma unroll
  for (int mt = 0; mt < 4; ++mt) {
    const int m0 = rowA0 + wm * 64 + mt * 16 + quad * 4;
#pragma unroll
    for (int nt = 0; nt < 4; ++nt) {
      const int col = rowB0 + wn * 64 + nt * 16 + lane16;
      const float bv = bias ? bias[col] : 0.f;
      if (writeT) {
        ushort4 o;
        o.x = f2bf(acc[mt][nt][0] + bv); o.y = f2bf(acc[mt][nt][1] + bv);
        o.z = f2bf(acc[mt][nt][2] + bv); o.w = f2bf(acc[mt][nt][3] + bv);
        *(ushort4*)(C + (size_t)col * M + m0) = o;
      } else {
#pragma unroll
        for (int j = 0; j < 4; ++j) C[(size_t)(m0 + j) * N + col] = f2bf(acc[mt][nt][j] + bv);
      }
    }
  }
}

// act2 layout (per parity buffer, 16384 qwords = 128 KB):
//   qword index = ks*512 + region*256 + wv*64 + lane
//   holds act[n = wv*16 + (lane&15)][k = ks*32 + (lane>>4)*8 + region*4 + (0..3)] bf16x4.
// Consumer wave wv, tile ks: two fully-contiguous 512 B loads (lane*8B) -> A-frag.
// Producer (block b owns h = b*8 .. b*8+7): thread (w,l) computes h = b*8+2w+{0,1},
// stores one packed dword at:  v=4*(b&3)+w; q=v>>2; r=(v>>1)&1; s=v&1;
//   dword = ( (b>>2)*512 + r*256 + (l>>4)*64 + q*16 + (l&15) )*2 + s
__global__ __launch_bounds__(256, 1) void lstm_rec(
    const unsigned short* __restrict__ preC,  // [4096][TCM] bf16
    const unsigned short* __restrict__ Wc,    // [4096][1024] bf16 (wr_w @ wo_w)
    const unsigned short* __restrict__ wo,    // [512][1024] bf16
    const float* __restrict__ wcp,            // [3072] peephole
    const void* __restrict__ lengths,         // int32 or int64 (auto-detected)
    unsigned long long* __restrict__ act2,    // [2][16384] qwords (zeroed)
    float* __restrict__ c_buf,                // [64][1024] f32 carry (zeroed)
    float* __restrict__ out,                  // [512][64][512]
    unsigned* __restrict__ bar,               // zeroed
    int t0, int t1, int last)
{
  __shared__ __align__(16) unsigned short Wc_lds[32 * 1032]; // 66 KB
  __shared__ float g_lds[64][33];                            // 8.4 KB  (74.5 KB total)
  const int tid = threadIdx.x, b = blockIdx.x;
  const int l = tid & 63, w = tid >> 6;
  const int lane16 = l & 15, quad = l >> 4;
  const int ptile = b & 31, kgr = b >> 5;     // kgr in 0..3 -> out replica group

  const int* L32 = (const int*)lengths;
  const bool is64 = (L32[1] == 0);

  // stage Wc: local row = gate*8 + hl  <-  Wc row gate*1024 + b*8 + hl
  for (int r = 0; r < 16; ++r) {
    int e = r * 256 + tid;
    int row = e >> 7, k = (e & 127) << 3;
    int gate = row >> 3, hl = row & 7;
    *(short8*)&Wc_lds[row * 1032 + k] =
        *(const short8*)&Wc[(size_t)(gate * 1024 + b * 8 + hl) * 1024 + k];
  }

  // gate-math thread (n=l, h = hb + kk, kk=0..1)
  const int hb = b * 8 + 2 * w;
  float cst[2], wci[2], wcf[2], wco[2];
#pragma unroll
  for (int kk = 0; kk < 2; ++kk) {
    cst[kk] = c_buf[l * HH + hb + kk];
    wci[kk] = wcp[hb + kk];
    wcf[kk] = wcp[1024 + hb + kk];
    wco[kk] = wcp[2048 + hb + kk];
  }
  // producer dword slot (constant across steps)
  const int v_ = (b & 3) * 4 + w;
  const int sq = v_ >> 2, sr = (v_ >> 1) & 1, ss = v_ & 1;
  const int pdw = ((b >> 2) * 512 + sr * 256 + (l >> 4) * 64 + sq * 16 + (l & 15)) * 2 + ss;
  unsigned* const act2dw = (unsigned*)act2;
  __syncthreads();

  for (int t = t0; t <= t1; ++t) {
    if (t == t1 && !last) break;
    const bool gate_on = (t < t1);

    float pv[4][2];
    if (gate_on) {
      const int trel = (t - t0) * NN + l;
#pragma unroll
      for (int g = 0; g < 4; ++g)
#pragma unroll
        for (int kk = 0; kk < 2; ++kk)
          pv[g][kk] = bf2f(preC[(size_t)(g * 1024 + hb + kk) * TCM + trel]);
    }

    // coherent act fragment loads: per wave per ks, two contiguous 512 B loads
    const unsigned long long* aP = act2 + (size_t)((t + 1) & 1) * 16384 + w * 64 + l;
    short8 frag[32];
#pragma unroll
    for (int ks = 0; ks < 32; ++ks) {
      unsigned long long lo = __hip_atomic_load(aP + ks * 512,       __ATOMIC_RELAXED, __HIP_MEMORY_SCOPE_AGENT);
      unsigned long long hi = __hip_atomic_load(aP + ks * 512 + 256, __ATOMIC_RELAXED, __HIP_MEMORY_SCOPE_AGENT);
      union { unsigned long long q[2]; short8 v; } u;
      u.q[0] = lo; u.q[1] = hi;
      frag[ks] = u.v;
    }

    floatx4 accg[2] = {};
#pragma unroll
    for (int ks = 0; ks < 32; ++ks) {
#pragma unroll
      for (int tt = 0; tt < 2; ++tt) {
        short8 bb = *(const short8*)&Wc_lds[(tt * 16 + lane16) * 1032 + ks * 32 + quad * 8];
        accg[tt] = __builtin_amdgcn_mfma_f32_16x16x32_bf16(frag[ks], bb, accg[tt], 0, 0, 0);
      }
    }

    // out projection for step t-1; 4 replica groups, wave w==kgr writes n rows [w*16,+16)
    if (w == kgr && t > 0) {
      floatx4 acco = {0.f, 0.f, 0.f, 0.f};
      const unsigned short* worow = wo + (size_t)(ptile * 16 + lane16) * 1024 + quad * 8;
#pragma unroll
      for (int ks = 0; ks < 32; ++ks) {
        short8 bo = *(const short8*)(worow + ks * 32);
        acco = __builtin_amdgcn_mfma_f32_16x16x32_bf16(frag[ks], bo, acco, 0, 0, 0);
      }
      const int p = ptile * 16 + lane16;
#pragma unroll
      for (int j = 0; j < 4; ++j) {
        const int n = w * 16 + quad * 4 + j;
        const int ln = is64 ? (int)((const long long*)lengths)[n] : L32[n];
        out[(size_t)((t - 1) * NN + n) * PP + p] = ((t - 1) < ln) ? acco[j] : 0.f;
      }
    }

    if (gate_on) {
      // dump g tiles: rows n = w*16+quad*4+j, cols c = tt*16+lane16 (c -> gate=c>>3, hl=c&7)
#pragma unroll
      for (int tt = 0; tt < 2; ++tt)
#pragma unroll
        for (int j = 0; j < 4; ++j)
          g_lds[w * 16 + quad * 4 + j][tt * 16 + lane16] = accg[tt][j];
      __syncthreads();

      unsigned packed = 0;
#pragma unroll
      for (int kk = 0; kk < 2; ++kk) {
        float gi = g_lds[l][0 * 8 + 2 * w + kk] + pv[0][kk];
        float gf = g_lds[l][1 * 8 + 2 * w + kk] + pv[1][kk];
        float go = g_lds[l][2 * 8 + 2 * w + kk] + pv[2][kk];
        float gc = g_lds[l][3 * 8 + 2 * w + kk] + pv[3][kk];
        float ig = sigm(gi + wci[kk] * cst[kk]);
        float fg = sigm(gf + wcf[kk] * cst[kk]);
        float cc = fg * cst[kk] + ig * tanha(gc);
        float og = sigm(go + wco[kk] * cc);
        cst[kk] = cc;
        packed |= (unsigned)f2bf(og * tanha(cc)) << (16 * kk);
      }
      __hip_atomic_store(act2dw + (size_t)(t & 1) * 32768 + pdw, packed,
                         __ATOMIC_RELAXED, __HIP_MEMORY_SCOPE_AGENT);

      __builtin_amdgcn_s_waitcnt(0);   // every wave drains its own coherent store
      __syncthreads();
      if (tid == 0) {
        __atomic_signal_fence(__ATOMIC_SEQ_CST);
        unsigned old = __hip_atomic_fetch_add(&bar[0], 1u, __ATOMIC_RELAXED, __HIP_MEMORY_SCOPE_AGENT);
        if (old == (unsigned)(t + 1) * NB - 1u) {
          __hip_atomic_store(&bar[1], (unsigned)(t + 1), __ATOMIC_RELAXED, __HIP_MEMORY_SCOPE_AGENT);
        } else {
          while (__hip_atomic_load(&bar[1], __ATOMIC_RELAXED, __HIP_MEMORY_SCOPE_AGENT) <= (unsigned)t)
            __builtin_amdgcn_s_sleep(1);
        }
        __atomic_signal_fence(__ATOMIC_SEQ_CST);
      }
      __syncthreads();
    }
  }
#pragma unroll
  for (int kk = 0; kk < 2; ++kk) c_buf[l * HH + hb + kk] = cst[kk];
}

extern "C" void kernel_launch(void* const* d_in, const int* in_sizes, int n_in,
                              void* d_out, int out_size, void* d_ws, size_t ws_size,
                              hipStream_t stream) {
  (void)in_sizes; (void)n_in; (void)out_size;
  const float* x    = (const float*)d_in[0];
  const void*  len  = d_in[1];
  const float* wx_w = (const float*)d_in[2];
  const float* wx_b = (const float*)d_in[3];
  const float* wr_w = (const float*)d_in[4];
  const float* wo_w = (const float*)d_in[5];
  const float* wc   = (const float*)d_in[6];
  float* out = (float*)d_out;

  char* ws = (char*)d_ws; size_t off = 0;
  auto alloc = [&](size_t b) { void* p = ws + off; off += (b + 255) & ~(size_t)255; return p; };
  unsigned short* x_bf  = (unsigned short*)alloc((size_t)MPRE * CC * 2);
  unsigned short* wx_bf = (unsigned short*)alloc((size_t)GG * CC * 2);
  unsigned short* wr_bf = (unsigned short*)alloc((size_t)GG * PP * 2);
  unsigned short* wo_bf = (unsigned short*)alloc((size_t)PP * HH * 2);
  unsigned short* woT   = (unsigned short*)alloc((size_t)HH * PP * 2);
  unsigned short* Wc_bf = (unsigned short*)alloc((size_t)GG * HH * 2);
  unsigned short* preC  = (unsigned short*)alloc((size_t)GG * TCM * 2);
  unsigned long long* act2 = (unsigned long long*)alloc((size_t)2 * 16384 * 8);
  float*          c_buf = (float*)alloc((size_t)NN * HH * 4);
  unsigned* bar = (unsigned*)alloc(256);
  if (off > ws_size) {
    fprintf(stderr, "kernel_launch: workspace too small (%zu needed, %zu given)\n", off, ws_size);
    return;
  }

  // zero act2 double-buffer + c carry + barrier (contiguous region)
  hipMemsetAsync(act2, 0, (size_t)2 * 16384 * 8 + (size_t)NN * HH * 4 + 256, stream);

  int n1 = MPRE * CC; cast_f32_bf16<<<dim3((n1 / 4 + 255) / 256), dim3(256), 0, stream>>>(x, x_bf, n1);
  int n2 = GG * CC;   cast_f32_bf16<<<dim3((n2 / 4 + 255) / 256), dim3(256), 0, stream>>>(wx_w, wx_bf, n2);
  int n3 = GG * PP;   cast_f32_bf16<<<dim3((n3 / 4 + 255) / 256), dim3(256), 0, stream>>>(wr_w, wr_bf, n3);
  int n4 = PP * HH;   cast_f32_bf16<<<dim3((n4 / 4 + 255) / 256), dim3(256), 0, stream>>>(wo_w, wo_bf, n4);
  transpose_cast<<<dim3((HH * PP + 255) / 256), dim3(256), 0, stream>>>(wo_w, woT);

  // W_comb = wr_w @ wo_w  (4096 x 1024)
  gemm_bt<<<dim3(GG / 128, HH / 128), dim3(256), 0, stream>>>(wr_bf, woT, nullptr, Wc_bf, GG, HH, PP, 0);

  for (int chunk = 0; chunk < TT / TC; ++chunk) {
    const int t0 = chunk * TC, t1 = t0 + TC;
    const int last = (t1 == TT) ? 1 : 0;
    gemm_bt<<<dim3(TCM / 128, GG / 128), dim3(256), 0, stream>>>(
        x_bf + (size_t)t0 * NN * CC, wx_bf, wx_b, preC, TCM, GG, CC, 1);

    const unsigned short* a0 = preC; const unsigned short* a1 = Wc_bf; const unsigned short* a2 = wo_bf;
    const float* a3 = wc; const void* a4 = len; unsigned long long* a5 = act2; float* a6c = c_buf;
    float* a7 = out; unsigned* a8 = bar; int a9 = t0, a10 = t1, a11 = last;
    void* args[12] = { &a0, &a1, &a2, &a3, &a4, &a5, &a6c, &a7, &a8, &a9, &a10, &a11 };
    hipError_t ce = hipLaunchCooperativeKernel((void*)lstm_rec, dim3(NB), dim3(256), args, 0, stream);
    if (ce != hipSuccess) {
      // fallback: plain launch (grid 128 <= 256 CUs -> co-resident; custom barrier, no grid.sync)
      lstm_rec<<<dim3(NB), dim3(256), 0, stream>>>(a0, a1, a2, a3, a4, a5, a6c, a7, a8, a9, a10, a11);
    }
  }
}